// Round 4
// baseline (86.502 us; speedup 1.0000x reference)
//
#include <hip/hip_runtime.h>

typedef short bf16x8 __attribute__((ext_vector_type(8)));
typedef float f32x4 __attribute__((ext_vector_type(4)));
typedef unsigned int u32x4 __attribute__((ext_vector_type(4)));
typedef unsigned short u16x4 __attribute__((ext_vector_type(4)));

__device__ __forceinline__ unsigned short f2bf(float f) {
  unsigned u = __builtin_bit_cast(unsigned, f);
  u = (u + 0x7FFFu + ((u >> 16) & 1u)) >> 16;   // RNE bf16
  return (unsigned short)u;
}

// ---------------- Kernel P: partial pooling sums + x -> bf16 cast ----------
__global__ __launch_bounds__(256) void k_pool_cvt(const float* __restrict__ x,
                                                  unsigned short* __restrict__ xb,
                                                  float* __restrict__ pp) {
  const int slice = blockIdx.x;       // 0..15
  const int b = blockIdx.y;           // 0..31
  const int t = threadIdx.x;
  const int c4 = (t & 31) * 4;
  const int seg = t >> 5;
  const size_t base = ((size_t)b * 4096 + slice * 256 + seg * 32) * 128;
  const float* xp = x + base;
  unsigned short* xbp = xb + base;
  f32x4 s = {0.f, 0.f, 0.f, 0.f};
  for (int p = 0; p < 32; ++p) {
    f32x4 v = *(const f32x4*)(xp + p * 128 + c4);
    s += v;
    u16x4 h;
    h.x = f2bf(v.x); h.y = f2bf(v.y); h.z = f2bf(v.z); h.w = f2bf(v.w);
    *(u16x4*)(xbp + p * 128 + c4) = h;
  }
  __shared__ f32x4 red[256];
  red[t] = s;
  __syncthreads();
  if (t < 32) {
    f32x4 tot = red[t];
#pragma unroll
    for (int g = 1; g < 8; ++g) tot += red[g * 32 + t];
    *(f32x4*)(pp + (size_t)(b * 16 + slice) * 128 + t * 4) = tot;
  }
}

// ---------------- Kernel R: finish pool, attention softmax, fused BN bias --
__global__ __launch_bounds__(128) void k_route(const float* __restrict__ pp,
    const float* __restrict__ redk, const float* __restrict__ attk,
    const float* __restrict__ bias, const float* __restrict__ bns,
    const float* __restrict__ bnb, const float* __restrict__ bnm,
    const float* __restrict__ bnv,
    float* __restrict__ att_ws, float* __restrict__ beta_ws,
    float* __restrict__ alpha_ws) {
  const int b = blockIdx.x, t = threadIdx.x;
  __shared__ float pool[128];
  __shared__ float att[4];
  {
    float s = 0.f;
    for (int i = 0; i < 16; ++i) s += pp[(size_t)(b * 16 + i) * 128 + t];
    pool[t] = s * (1.f / 4096.f);
  }
  __syncthreads();
  if (t == 0) {
    float pr[4];
    for (int r = 0; r < 4; ++r) {
      float s = 0.f;
      for (int c = 0; c < 128; ++c) s += pool[c] * redk[c * 4 + r];
      pr[r] = fmaxf(s, 0.f);
    }
    float lgt[4]; float mx = -1e30f;
    for (int k = 0; k < 4; ++k) {
      float s = 0.f;
      for (int r = 0; r < 4; ++r) s += pr[r] * attk[r * 4 + k];
      lgt[k] = s * (1.f / 30.f);
      mx = fmaxf(mx, lgt[k]);
    }
    float den = 0.f;
    for (int k = 0; k < 4; ++k) { lgt[k] = expf(lgt[k] - mx); den += lgt[k]; }
    for (int k = 0; k < 4; ++k) { att[k] = lgt[k] / den; att_ws[b * 4 + k] = att[k]; }
  }
  __syncthreads();
  {
    float bm = 0.f;
    for (int k = 0; k < 4; ++k) bm += att[k] * bias[k * 128 + t];
    const float inv = bns[t] * rsqrtf(bnv[t] + 1e-5f);
    beta_ws[b * 128 + t] = (bm - bnm[t]) * inv + bnb[t];
    alpha_ws[t] = inv;
  }
}

// ---------------- Kernel W: mix experts -> w_ws[b][h][tap][kc][128f][32c] --
// 16-B chunk granularity; B-fragment for (f, kc) is then a fully coalesced
// 1 KB wave read in k_conv (f*32 + lg*8 within a 4096-short slab).
__global__ __launch_bounds__(256) void k_mixw(const float* __restrict__ ck,
                                              const float* __restrict__ att_ws,
                                              unsigned short* __restrict__ w_ws) {
  const int tap = blockIdx.x;   // 0..8
  const int b = blockIdx.y;     // 0..31
  const int t = threadIdx.x;
  const float a0 = att_ws[b * 4 + 0], a1 = att_ws[b * 4 + 1];
  const float a2 = att_ws[b * 4 + 2], a3 = att_ws[b * 4 + 3];
  const float* ckp = ck + (size_t)tap * 16384;
  __shared__ unsigned short lds_t[128 * 136];   // [f][c], padded row
#pragma unroll 4
  for (int it = 0; it < 16; ++it) {
    const int i4 = t + it * 256;          // f32x4 index (4096 total)
    const int idx = i4 * 4;               // c = idx>>7, f = idx&127 (4-aligned)
    const int c = idx >> 7, f = idx & 127;
    f32x4 v0 = *(const f32x4*)(ckp + idx);
    f32x4 v1 = *(const f32x4*)(ckp + idx + 147456);
    f32x4 v2 = *(const f32x4*)(ckp + idx + 2 * 147456);
    f32x4 v3 = *(const f32x4*)(ckp + idx + 3 * 147456);
#pragma unroll
    for (int e = 0; e < 4; ++e)
      lds_t[(f + e) * 136 + c] = f2bf(a0 * v0[e] + a1 * v1[e] + a2 * v2[e] + a3 * v3[e]);
  }
  __syncthreads();
  unsigned short* wb = w_ws + (size_t)b * 147456;
#pragma unroll
  for (int it = 0; it < 8; ++it) {
    const int m = t + it * 256;           // 2048 chunks total
    const int f = m >> 4, o = m & 15;     // o = c-oct over 128 ch
    const int h = o >> 3;                 // channel half
    const int cp = (o & 7) * 8;           // c within half, 0..56
    const int kc = cp >> 5;               // 32-ch quarter within half
    const int c2 = cp & 31;
    unsigned short* dst = wb + ((size_t)(((h * 9 + tap) * 2 + kc) * 128 + f)) * 32 + c2;
    *(bf16x8*)dst = *(const bf16x8*)(lds_t + f * 136 + o * 8);
  }
}

// ---------------- Kernel C: 3x3 conv, barrier-free main loop ---------------
// 1024 blocks (32 samples x 32 row-pairs), 256 thr = 4 waves (2 wm x 2 wn).
// Block tile M=128 px (2 rows) x N=128 f. Wave tile 64x64 (4x4 16x16 frags).
// x: persistent 32 KB LDS tile (4 rows x 64 px x 64 ch, XOR-swizzled via
// pre-swizzled global source). Weights: NEVER in LDS — per-wave VGPR
// double-buffer, prefetched 1 step ahead from L2 (coalesced 1 KB/wave-load).
// Only 2 barriers total (prologue + half-switch restage). 3 blocks/CU.
__device__ __forceinline__ void stage_x(char* xt, const unsigned short* xbp,
                                        int r0, int h, int t) {
#pragma unroll
  for (int j = 0; j < 8; ++j) {
    const int i = t + j * 256;            // 16B chunk, 2048 total
    const int jr = i >> 9;                // row 0..3 (wave-uniform)
    const int pix = (i & 511) >> 3;
    const int oct = i & 7;
    const int soct = oct ^ (pix & 7);     // pre-swizzled source oct
    const int rr = r0 - 1 + jr;
    char* dst = xt + i * 16;              // linear LDS dest
    if ((unsigned)rr < 64u) {
      __builtin_amdgcn_global_load_lds(
          (const __attribute__((address_space(1))) void*)
              (xbp + ((size_t)(rr * 64 + pix)) * 128 + h * 64 + soct * 8),
          (__attribute__((address_space(3))) void*)dst, 16, 0, 0);
    } else {
      *(u32x4*)dst = (u32x4){0, 0, 0, 0};
    }
  }
}

#define LOADB(dst, u)                                                          \
  {                                                                            \
    const unsigned short* wp = wsrc + (size_t)(u) * 4096;                      \
    _Pragma("unroll")                                                          \
    for (int nf = 0; nf < 4; ++nf) {                                           \
      const int f = wn * 64 + nf * 16 + lr;                                    \
      dst[nf] = *(const bf16x8*)(wp + f * 32 + lg * 8);                        \
    }                                                                          \
  }

#define COMPUTE(kc, bfr)                                                       \
  {                                                                            \
    bf16x8 afr[4];                                                             \
    _Pragma("unroll")                                                          \
    for (int mf = 0; mf < 4; ++mf) {                                           \
      const int col = mf * 16 + lr + dw;                                       \
      const int a = (((jrow * 64 + col) * 128 + (kc) * 64 + lg * 16))          \
                    ^ ((col & 7) << 4);                                        \
      afr[mf] = ((unsigned)col < 64u) ? *(const bf16x8*)(xt + a) : zero;       \
    }                                                                          \
    _Pragma("unroll")                                                          \
    for (int mf = 0; mf < 4; ++mf)                                             \
      _Pragma("unroll")                                                        \
      for (int nf = 0; nf < 4; ++nf)                                           \
        acc[mf][nf] = __builtin_amdgcn_mfma_f32_16x16x32_bf16(afr[mf],         \
                          bfr[nf], acc[mf][nf], 0, 0, 0);                      \
  }

__global__ __launch_bounds__(256, 3) void k_conv(const unsigned short* __restrict__ xb,
                                                 const unsigned short* __restrict__ w_ws,
                                                 const float* __restrict__ alpha_ws,
                                                 const float* __restrict__ beta_ws,
                                                 float* __restrict__ out) {
  __shared__ char xt[32768];      // 4 rows x 64 px x 64 ch bf16, swizzled

  const int orig = blockIdx.x;
  const int wg = (orig & 7) * 128 + (orig >> 3);  // XCD-chunked, bijective
  const int b = wg >> 5;          // sample
  const int tile = wg & 31;       // row pair
  const int t = threadIdx.x;
  const int lane = t & 63, wid = t >> 6;
  const int wm = wid >> 1, wn = wid & 1;          // 2x2 waves
  const int lr = lane & 15, lg = lane >> 4;
  const int r0 = tile * 2;

  const unsigned short* xbp = xb + (size_t)b * 4096 * 128;
  const unsigned short* wsrc = w_ws + (size_t)b * 147456;

  f32x4 acc[4][4] = {};
  const bf16x8 zero = {};
  bf16x8 bA[4], bB[4];

  stage_x(xt, xbp, r0, 0, t);
  LOADB(bA, 0);
  __syncthreads();                // drain x stage (+ bA in flight is fine)

  for (int u = 0; u < 36; u += 2) {   // u = (h*9+tap)*2 + kc, kc pairs
    const int tap = (u >> 1) % 9;
    const int dh = tap / 3 - 1, dw = tap % 3 - 1;
    const int jrow = wm + dh + 1;     // 0..3 within xt
    LOADB(bB, u + 1);
    COMPUTE(0, bA);
    LOADB(bA, (u + 2 < 36) ? (u + 2) : 35);
    COMPUTE(1, bB);
    if (u == 16) {                    // half 0 done -> restage channels 64..127
      __syncthreads();
      stage_x(xt, xbp, r0, 1, t);
      __syncthreads();
    }
  }

  // Fused epilogue: relu(acc * inv + beta)
  float af[4], bt[4];
#pragma unroll
  for (int nf = 0; nf < 4; ++nf) {
    const int f = wn * 64 + nf * 16 + lr;
    af[nf] = alpha_ws[f];
    bt[nf] = beta_ws[b * 128 + f];
  }
  float* op = out + (size_t)b * 4096 * 128;
  const int row = r0 + wm;
#pragma unroll
  for (int mf = 0; mf < 4; ++mf) {
#pragma unroll
    for (int r = 0; r < 4; ++r) {
      const int col = mf * 16 + lg * 4 + r;       // C/D: row-in-frag = lg*4+reg
#pragma unroll
      for (int nf = 0; nf < 4; ++nf) {
        const int f = wn * 64 + nf * 16 + lr;     // C/D: col-in-frag = lane&15
        const float v = acc[mf][nf][r] * af[nf] + bt[nf];
        op[(size_t)(row * 64 + col) * 128 + f] = fmaxf(v, 0.f);
      }
    }
  }
}

extern "C" void kernel_launch(void* const* d_in, const int* in_sizes, int n_in,
                              void* d_out, int out_size, void* d_ws, size_t ws_size,
                              hipStream_t stream) {
  const float* x    = (const float*)d_in[0];
  const float* redk = (const float*)d_in[1];
  const float* attk = (const float*)d_in[2];
  const float* ck   = (const float*)d_in[3];
  const float* bias = (const float*)d_in[4];
  const float* bns  = (const float*)d_in[5];
  const float* bnbb = (const float*)d_in[6];
  const float* bnm  = (const float*)d_in[7];
  const float* bnv  = (const float*)d_in[8];
  float* out = (float*)d_out;

  char* ws = (char*)d_ws;
  unsigned short* xb   = (unsigned short*)ws;                  // 33,554,432 B
  unsigned short* w_ws = (unsigned short*)(ws + 33554432);     //  9,437,184 B
  float* pp       = (float*)(ws + 42991616);                   //    262,144 B
  float* att_ws   = (float*)(ws + 43253760);
  float* beta_ws  = (float*)(ws + 43254272);
  float* alpha_ws = (float*)(ws + 43270656);

  k_pool_cvt<<<dim3(16, 32), 256, 0, stream>>>(x, xb, pp);
  k_route<<<32, 128, 0, stream>>>(pp, redk, attk, bias, bns, bnbb, bnm, bnv,
                                  att_ws, beta_ws, alpha_ws);
  k_mixw<<<dim3(9, 32), 256, 0, stream>>>(ck, att_ws, w_ws);
  k_conv<<<1024, 256, 0, stream>>>(xb, w_ws, alpha_ws, beta_ws, out);
}

// Round 5
// 83.031 us; speedup vs baseline: 1.0418x; 1.0418x over previous
//
#include <hip/hip_runtime.h>

typedef short bf16x8 __attribute__((ext_vector_type(8)));
typedef float f32x4 __attribute__((ext_vector_type(4)));
typedef unsigned int u32x4 __attribute__((ext_vector_type(4)));
typedef unsigned short u16x4 __attribute__((ext_vector_type(4)));

__device__ __forceinline__ unsigned short f2bf(float f) {
  unsigned u = __builtin_bit_cast(unsigned, f);
  u = (u + 0x7FFFu + ((u >> 16) & 1u)) >> 16;   // RNE bf16
  return (unsigned short)u;
}

// ---------------- Kernel P: partial pooling sums + x -> bf16 cast ----------
__global__ __launch_bounds__(256) void k_pool_cvt(const float* __restrict__ x,
                                                  unsigned short* __restrict__ xb,
                                                  float* __restrict__ pp) {
  const int slice = blockIdx.x;       // 0..15
  const int b = blockIdx.y;           // 0..31
  const int t = threadIdx.x;
  const int c4 = (t & 31) * 4;
  const int seg = t >> 5;
  const size_t base = ((size_t)b * 4096 + slice * 256 + seg * 32) * 128;
  const float* xp = x + base;
  unsigned short* xbp = xb + base;
  f32x4 s = {0.f, 0.f, 0.f, 0.f};
  for (int p = 0; p < 32; ++p) {
    f32x4 v = *(const f32x4*)(xp + p * 128 + c4);
    s += v;
    u16x4 h;
    h.x = f2bf(v.x); h.y = f2bf(v.y); h.z = f2bf(v.z); h.w = f2bf(v.w);
    *(u16x4*)(xbp + p * 128 + c4) = h;
  }
  __shared__ f32x4 red[256];
  red[t] = s;
  __syncthreads();
  if (t < 32) {
    f32x4 tot = red[t];
#pragma unroll
    for (int g = 1; g < 8; ++g) tot += red[g * 32 + t];
    *(f32x4*)(pp + (size_t)(b * 16 + slice) * 128 + t * 4) = tot;
  }
}

// ---------------- Kernel R: finish pool, attention softmax, fused BN bias --
__global__ __launch_bounds__(128) void k_route(const float* __restrict__ pp,
    const float* __restrict__ redk, const float* __restrict__ attk,
    const float* __restrict__ bias, const float* __restrict__ bns,
    const float* __restrict__ bnb, const float* __restrict__ bnm,
    const float* __restrict__ bnv,
    float* __restrict__ att_ws, float* __restrict__ beta_ws,
    float* __restrict__ alpha_ws) {
  const int b = blockIdx.x, t = threadIdx.x;
  __shared__ float pool[128];
  __shared__ float att[4];
  {
    float s = 0.f;
    for (int i = 0; i < 16; ++i) s += pp[(size_t)(b * 16 + i) * 128 + t];
    pool[t] = s * (1.f / 4096.f);
  }
  __syncthreads();
  if (t == 0) {
    float pr[4];
    for (int r = 0; r < 4; ++r) {
      float s = 0.f;
      for (int c = 0; c < 128; ++c) s += pool[c] * redk[c * 4 + r];
      pr[r] = fmaxf(s, 0.f);
    }
    float lgt[4]; float mx = -1e30f;
    for (int k = 0; k < 4; ++k) {
      float s = 0.f;
      for (int r = 0; r < 4; ++r) s += pr[r] * attk[r * 4 + k];
      lgt[k] = s * (1.f / 30.f);
      mx = fmaxf(mx, lgt[k]);
    }
    float den = 0.f;
    for (int k = 0; k < 4; ++k) { lgt[k] = expf(lgt[k] - mx); den += lgt[k]; }
    for (int k = 0; k < 4; ++k) { att[k] = lgt[k] / den; att_ws[b * 4 + k] = att[k]; }
  }
  __syncthreads();
  {
    float bm = 0.f;
    for (int k = 0; k < 4; ++k) bm += att[k] * bias[k * 128 + t];
    const float inv = bns[t] * rsqrtf(bnv[t] + 1e-5f);
    beta_ws[b * 128 + t] = (bm - bnm[t]) * inv + bnb[t];
    alpha_ws[t] = inv;
  }
}

// ---------------- Kernel W: mix experts -> w_ws[b][h*9+tap] 16KB slabs -----
// Slab = [128 f][8 c-oct] 16B chunks, PRE-SWIZZLED: chunk (f, o) stored at
// f*8 + (o ^ (f&7)); k_conv DMAs linearly and reads with addr ^ ((f&7)<<4).
__global__ __launch_bounds__(256) void k_mixw(const float* __restrict__ ck,
                                              const float* __restrict__ att_ws,
                                              unsigned short* __restrict__ w_ws) {
  const int tap = blockIdx.x;   // 0..8
  const int b = blockIdx.y;     // 0..31
  const int t = threadIdx.x;
  const float a0 = att_ws[b * 4 + 0], a1 = att_ws[b * 4 + 1];
  const float a2 = att_ws[b * 4 + 2], a3 = att_ws[b * 4 + 3];
  const float* ckp = ck + (size_t)tap * 16384;
  __shared__ unsigned short lds_t[128 * 136];   // [f][c], padded row
#pragma unroll 4
  for (int it = 0; it < 16; ++it) {
    const int i4 = t + it * 256;          // f32x4 index (4096 total)
    const int idx = i4 * 4;               // c = idx>>7, f = idx&127 (4-aligned)
    const int c = idx >> 7, f = idx & 127;
    f32x4 v0 = *(const f32x4*)(ckp + idx);
    f32x4 v1 = *(const f32x4*)(ckp + idx + 147456);
    f32x4 v2 = *(const f32x4*)(ckp + idx + 2 * 147456);
    f32x4 v3 = *(const f32x4*)(ckp + idx + 3 * 147456);
#pragma unroll
    for (int e = 0; e < 4; ++e)
      lds_t[(f + e) * 136 + c] = f2bf(a0 * v0[e] + a1 * v1[e] + a2 * v2[e] + a3 * v3[e]);
  }
  __syncthreads();
#pragma unroll
  for (int it = 0; it < 8; ++it) {
    const int m = t + it * 256;           // 2048 chunks total
    const int f = m >> 4, oo = m & 15;    // oo = c-oct over 128 ch
    const int h = oo >> 3, o = oo & 7;    // half, oct-within-half
    unsigned short* dst = w_ws + ((size_t)b * 18 + h * 9 + tap) * 8192
                        + (size_t)(f * 8 + (o ^ (f & 7))) * 8;
    *(bf16x8*)dst = *(const bf16x8*)(lds_t + f * 136 + oo * 8);
  }
}

// ---------------- Kernel C: 3x3 conv, counted-vmcnt pipelined schedule -----
// 512 blocks (32 samples x 16 row-quads), 512 thr = 8 waves (4 wm x 2 wn).
// M = 4 rows x 64 px, N = 128 f. 18 slabs (2 ch-halves x 9 taps).
// LDS 80 KB: xt 48 KB (6 rows x 64 px x 64 ch, swizzled via pre-swizzled
// source) + 2 x 16 KB weight slabs. 2 blocks/CU (16 waves).
// T3+T4: per tap, issue slab s+1, s_waitcnt vmcnt(2) (slab s only — s+1
// stays in flight across the barrier), raw s_barrier, MFMA cluster (T5
// setprio), end barrier. vmcnt never drains to 0 in the main loop.
__device__ __forceinline__ void stage_w16(char* dst, const unsigned short* src, int t) {
#pragma unroll
  for (int j = 0; j < 2; ++j) {
    const int i = t + j * 512;            // 16B chunk, 1024 total
    __builtin_amdgcn_global_load_lds(
        (const __attribute__((address_space(1))) void*)(src + (size_t)i * 8),
        (__attribute__((address_space(3))) void*)(dst + i * 16), 16, 0, 0);
  }
}

__device__ __forceinline__ void stage_x_half(char* xt, const unsigned short* xbp,
                                             int r0, int h, int t) {
  const int pix = t >> 3;                             // 0..63
  const int oct = (t & 7) ^ ((t >> 3) & 7);           // pre-swizzled source oct
#pragma unroll
  for (int j = 0; j < 6; ++j) {
    const int rr = r0 - 1 + j;
    char* dst = xt + j * 8192 + t * 16;               // linear LDS dest
    if ((unsigned)rr < 64u) {
      __builtin_amdgcn_global_load_lds(
          (const __attribute__((address_space(1))) void*)
              (xbp + ((size_t)(rr * 64 + pix)) * 128 + h * 64 + oct * 8),
          (__attribute__((address_space(3))) void*)dst, 16, 0, 0);
    } else {
      *(u32x4*)dst = (u32x4){0, 0, 0, 0};             // zero padding row
    }
  }
}

__global__ __launch_bounds__(512, 4) void k_conv(const unsigned short* __restrict__ xb,
                                                 const unsigned short* __restrict__ w_ws,
                                                 const float* __restrict__ alpha_ws,
                                                 const float* __restrict__ beta_ws,
                                                 float* __restrict__ out) {
  extern __shared__ char lds[];           // 81920 B
  char* xt = lds;                         // 49152 B
  char* wlds = lds + 49152;               // 2 x 16384 B

  const int orig = blockIdx.x;
  const int wg = (orig & 7) * 64 + (orig >> 3);   // XCD-chunked, bijective
  const int b = wg >> 4;
  const int tile = wg & 15;
  const int t = threadIdx.x;
  const int lane = t & 63, wid = t >> 6;
  const int wm = wid >> 1, wn = wid & 1;          // wave -> (row, f-half)
  const int lr = lane & 15, lg = lane >> 4;
  const int r0 = tile * 4;

  const unsigned short* xbp = xb + (size_t)b * 4096 * 128;
  const unsigned short* wsrc = w_ws + (size_t)b * 18 * 8192;

  f32x4 acc[4][4] = {};
  const bf16x8 zero = {};

  // Prologue: x half 0 + slab 0; full drain (pad ds_writes need lgkmcnt).
  stage_x_half(xt, xbp, r0, 0, t);
  stage_w16(wlds, wsrc, t);
  asm volatile("s_waitcnt vmcnt(0) lgkmcnt(0)" ::: "memory");
  __builtin_amdgcn_s_barrier();
  asm volatile("" ::: "memory");

  for (int s = 0; s < 18; ++s) {
    const int tap = s % 9;
    char* cb = wlds + ((s & 1) << 14);
    // Issue next stages (destinations freed by end-of-iter s-1 barrier).
    if (s == 9) stage_x_half(xt, xbp, r0, 1, t);        // channel-half switch
    if (s < 17) stage_w16(wlds + (((s + 1) & 1) << 14),
                          wsrc + (size_t)(s + 1) * 8192, t);
    // Wait slab s (+ x at s==9); leave slab s+1's 2 loads in flight.
    if (s == 9)       asm volatile("s_waitcnt vmcnt(2) lgkmcnt(0)" ::: "memory");
    else if (s < 17)  asm volatile("s_waitcnt vmcnt(2)" ::: "memory");
    else              asm volatile("s_waitcnt vmcnt(0)" ::: "memory");
    __builtin_amdgcn_s_barrier();
    asm volatile("" ::: "memory");   // no LDS reads hoisted above barrier

    const int dh = tap / 3 - 1, dw = tap % 3 - 1;
    const int jrow = wm + dh + 1;                 // 0..5 within xt
#pragma unroll
    for (int kc = 0; kc < 2; ++kc) {
      bf16x8 afr[4], bfr[4];
#pragma unroll
      for (int mf = 0; mf < 4; ++mf) {
        const int col = mf * 16 + lr + dw;        // -1..64
        const int a = ((jrow * 64 + col) * 128 + kc * 64 + lg * 16) ^ ((col & 7) << 4);
        afr[mf] = ((unsigned)col < 64u) ? *(const bf16x8*)(xt + a) : zero;
      }
#pragma unroll
      for (int nf = 0; nf < 4; ++nf) {
        const int f = wn * 64 + nf * 16 + lr;
        const int a = (f * 128 + kc * 64 + lg * 16) ^ ((f & 7) << 4);
        bfr[nf] = *(const bf16x8*)(cb + a);
      }
      __builtin_amdgcn_s_setprio(1);
#pragma unroll
      for (int mf = 0; mf < 4; ++mf)
#pragma unroll
        for (int nf = 0; nf < 4; ++nf)
          acc[mf][nf] = __builtin_amdgcn_mfma_f32_16x16x32_bf16(afr[mf], bfr[nf],
                                                                acc[mf][nf], 0, 0, 0);
      __builtin_amdgcn_s_setprio(0);
    }
    asm volatile("" ::: "memory");   // no LDS reads sunk below barrier
    __builtin_amdgcn_s_barrier();    // readers done before next overwrite
  }

  // Fused epilogue: relu(acc * inv + beta)
  float af[4], bt[4];
#pragma unroll
  for (int nf = 0; nf < 4; ++nf) {
    const int f = wn * 64 + nf * 16 + lr;
    af[nf] = alpha_ws[f];
    bt[nf] = beta_ws[b * 128 + f];
  }
  float* op = out + (size_t)b * 4096 * 128;
  const int row = r0 + wm;
#pragma unroll
  for (int mf = 0; mf < 4; ++mf) {
#pragma unroll
    for (int r = 0; r < 4; ++r) {
      const int col = mf * 16 + lg * 4 + r;       // C/D: row-in-frag = lg*4+reg
#pragma unroll
      for (int nf = 0; nf < 4; ++nf) {
        const int f = wn * 64 + nf * 16 + lr;     // C/D: col-in-frag = lane&15
        const float v = acc[mf][nf][r] * af[nf] + bt[nf];
        op[(size_t)(row * 64 + col) * 128 + f] = fmaxf(v, 0.f);
      }
    }
  }
}

extern "C" void kernel_launch(void* const* d_in, const int* in_sizes, int n_in,
                              void* d_out, int out_size, void* d_ws, size_t ws_size,
                              hipStream_t stream) {
  const float* x    = (const float*)d_in[0];
  const float* redk = (const float*)d_in[1];
  const float* attk = (const float*)d_in[2];
  const float* ck   = (const float*)d_in[3];
  const float* bias = (const float*)d_in[4];
  const float* bns  = (const float*)d_in[5];
  const float* bnbb = (const float*)d_in[6];
  const float* bnm  = (const float*)d_in[7];
  const float* bnv  = (const float*)d_in[8];
  float* out = (float*)d_out;

  char* ws = (char*)d_ws;
  unsigned short* xb   = (unsigned short*)ws;                  // 33,554,432 B
  unsigned short* w_ws = (unsigned short*)(ws + 33554432);     //  9,437,184 B
  float* pp       = (float*)(ws + 42991616);                   //    262,144 B
  float* att_ws   = (float*)(ws + 43253760);
  float* beta_ws  = (float*)(ws + 43254272);
  float* alpha_ws = (float*)(ws + 43270656);

  k_pool_cvt<<<dim3(16, 32), 256, 0, stream>>>(x, xb, pp);
  k_route<<<32, 128, 0, stream>>>(pp, redk, attk, bias, bns, bnbb, bnm, bnv,
                                  att_ws, beta_ws, alpha_ws);
  k_mixw<<<dim3(9, 32), 256, 0, stream>>>(ck, att_ws, w_ws);
  k_conv<<<512, 512, 81920, stream>>>(xb, w_ws, alpha_ws, beta_ws, out);
}